// Round 5
// baseline (115.198 us; speedup 1.0000x reference)
//
#include <hip/hip_runtime.h>

#define K_TOP 205
#define ROW   4096
#define NTHR  256
#define RPB   4              // rows per block (one row per wave)
#define CAP   384            // candidate slots per wave (mean M=169, sd 12.7)
#define NSLOT (CAP / 64)

#define FLO 1.45f            // bracket the 95th percentile of N(0,1)
#define FHI 1.85f

typedef float fx4 __attribute__((ext_vector_type(4)));

__device__ __forceinline__ unsigned key_of_bits(unsigned b) {
    return b ^ (((unsigned)((int)b >> 31)) | 0x80000000u);
}
__device__ __forceinline__ float val_of(unsigned u) {
    return __uint_as_float(u ^ ((u & 0x80000000u) ? 0x80000000u : 0xFFFFFFFFu));
}
__device__ __forceinline__ unsigned wave_sum(unsigned v) {
#pragma unroll
    for (int off = 1; off < 64; off <<= 1) v += __shfl_xor(v, off, 64);
    return v;
}

__global__ __launch_bounds__(NTHR, 8)   // force VGPR<=64 -> 8 waves/SIMD, 32 rows/CU
void kwta_kernel(const float* __restrict__ x, float* __restrict__ out) {
    __shared__ float cand[RPB][CAP];

    const int lane = (int)(threadIdx.x & 63u);
    const int wave = (int)(threadIdx.x >> 6u);
    const long long row = (long long)blockIdx.x * RPB + wave;

    const fx4* __restrict__ xin = (const fx4*)(x + row * (long long)ROW);
    const unsigned long long lmask_lt = (1ull << lane) - 1ull;

    // zero candidate slots (unwritten tail must compare < FLO)
#pragma unroll
    for (int s = 0; s < NSLOT; ++s) cand[wave][lane + 64 * s] = 0.0f;

    // ---- pass 1: stream row, ballot-count vs pivots, compact window to LDS ----
    unsigned c_lo = 0, c_hi = 0, base = 0;
#pragma unroll 4
    for (int j = 0; j < 16; ++j) {
        fx4 v = xin[j * 64 + lane];            // cacheable: we re-read from L2 later
#pragma unroll
        for (int c = 0; c < 4; ++c) {
            float e = v[c];
            unsigned long long mlo = __ballot(e >= FLO);
            unsigned long long mhi = __ballot(e >= FHI);
            unsigned long long mw  = mlo & ~mhi;
            if (e >= FLO && e < FHI) {
                unsigned slot = base + (unsigned)__popcll(mw & lmask_lt);
                if (slot < CAP) cand[wave][slot] = e;   // guard: no OOB into next wave
            }
            base += (unsigned)__popcll(mw);             // uniform (SALU)
            c_lo += (unsigned)__popcll(mlo);
            c_hi += (unsigned)__popcll(mhi);
        }
    }
    const unsigned M = c_lo - c_hi;

    float Tf; unsigned S, Sex;                 // threshold value, #>=T, #>T

    const bool fast = (c_lo >= K_TOP) && (c_hi < K_TOP) && (M <= CAP);
    if (fast) {
        float cs[NSLOT];
#pragma unroll
        for (int s = 0; s < NSLOT; ++s) cs[s] = cand[wave][lane + 64 * s];

        const unsigned KLO = key_of_bits(__float_as_uint(FLO));
        const unsigned KHI = key_of_bits(__float_as_uint(FHI));
        unsigned lo = KLO, hi = KHI, cl = c_lo, ch = c_hi;
        while (hi - lo > 1u) {
            unsigned mid = lo + ((hi - lo) >> 1);
            float mf = val_of(mid);            // uniform scalar
            unsigned c = c_hi;
#pragma unroll
            for (int s = 0; s < NSLOT; ++s)
                c += (unsigned)__popcll(__ballot(cs[s] >= mf));
            if (c >= K_TOP) { lo = mid; cl = c; } else { hi = mid; ch = c; }
        }
        Tf = val_of(lo); S = cl; Sex = ch;
    } else {
        // ---- rare exact fallback: full-key bisection, re-reading row each iter ----
        unsigned lo = 0u, hi = 0xFFFFFFFFu, cl = ROW, ch;
        {
            unsigned cc = 0;
            for (int j = 0; j < 16; ++j) {
                fx4 v = xin[j * 64 + lane];
#pragma unroll
                for (int c = 0; c < 4; ++c)
                    cc += (unsigned)(key_of_bits(__float_as_uint(v[c])) >= hi);
            }
            ch = wave_sum(cc);
        }
        if (ch >= K_TOP) { lo = hi; cl = ch; ch = 0; }
        else {
            while (hi - lo > 1u) {
                asm volatile("" ::: "memory");   // force reload, bound reg pressure
                unsigned mid = lo + ((hi - lo) >> 1);
                unsigned cc = 0;
                for (int j = 0; j < 16; ++j) {
                    fx4 v = xin[j * 64 + lane];
#pragma unroll
                    for (int c = 0; c < 4; ++c)
                        cc += (unsigned)(key_of_bits(__float_as_uint(v[c])) >= mid);
                }
                cc = wave_sum(cc);
                if (cc >= K_TOP) { lo = mid; cl = cc; } else { hi = mid; ch = cc; }
            }
        }
        Tf = val_of(lo); S = cl; Sex = ch;
    }

    const unsigned r  = K_TOP - Sex;           // ties (== Tf) kept, lowest index first
    const unsigned eq = S - Sex;               // total ties

    asm volatile("" ::: "memory");             // block CSE of pass-2 loads with pass 1

    fx4* __restrict__ o = (fx4*)(out + row * (long long)ROW);

    if (eq == r) {
        // common case: keep everything >= Tf; re-read row (L2 hit), NT store
#pragma unroll 4
        for (int j = 0; j < 16; ++j) {
            fx4 v = xin[j * 64 + lane], w;
            w.x = (v.x >= Tf) ? v.x : 0.0f;
            w.y = (v.y >= Tf) ? v.y : 0.0f;
            w.z = (v.z >= Tf) ? v.z : 0.0f;
            w.w = (v.w >= Tf) ? v.w : 0.0f;
            __builtin_nontemporal_store(w, &o[j * 64 + lane]);
        }
    } else {
        // rare: rank ties by flat index (j, lane, c), keep the first r
        unsigned rank_base = 0;
        for (int j = 0; j < 16; ++j) {
            fx4 v = xin[j * 64 + lane];
            unsigned e = (unsigned)(v.x == Tf) + (unsigned)(v.y == Tf)
                       + (unsigned)(v.z == Tf) + (unsigned)(v.w == Tf);
            unsigned inc = e;
#pragma unroll
            for (int off = 1; off < 64; off <<= 1) {
                unsigned n = __shfl_up(inc, off, 64);
                if (lane >= off) inc += n;
            }
            unsigned rk  = rank_base + (inc - e);        // exclusive prefix
            unsigned tot = __shfl(inc, 63, 64);          // chunk total

            fx4 w;
            if (v.x == Tf) { w.x = (rk < r) ? v.x : 0.0f; ++rk; }
            else           { w.x = (v.x > Tf) ? v.x : 0.0f; }
            if (v.y == Tf) { w.y = (rk < r) ? v.y : 0.0f; ++rk; }
            else           { w.y = (v.y > Tf) ? v.y : 0.0f; }
            if (v.z == Tf) { w.z = (rk < r) ? v.z : 0.0f; ++rk; }
            else           { w.z = (v.z > Tf) ? v.z : 0.0f; }
            if (v.w == Tf) { w.w = (rk < r) ? v.w : 0.0f; ++rk; }
            else           { w.w = (v.w > Tf) ? v.w : 0.0f; }
            __builtin_nontemporal_store(w, &o[j * 64 + lane]);

            rank_base += tot;
        }
    }
}

extern "C" void kernel_launch(void* const* d_in, const int* in_sizes, int n_in,
                              void* d_out, int out_size, void* d_ws, size_t ws_size,
                              hipStream_t stream) {
    const float* x = (const float*)d_in[0];
    float* out = (float*)d_out;
    const int rows = out_size / ROW;           // 16384
    kwta_kernel<<<rows / RPB, NTHR, 0, stream>>>(x, out);
}